// Round 5
// baseline (207.657 us; speedup 1.0000x reference)
//
#include <hip/hip_runtime.h>
#include <hip/hip_bf16.h>
#include <math.h>

// Problem constants (from reference): N=10000, E=50000, D=32, H=4, DH=8
#define DD 32
#define HH 4
#define EPB 16   // edges per block (pipelined)

__device__ __forceinline__ void atomicMaxFloat(float* addr, float val) {
    // sign-split trick; addr must be initialized to -inf
    if (val >= 0.0f) {
        atomicMax((int*)addr, __float_as_int(val));
    } else {
        atomicMin((unsigned int*)addr, __float_as_uint(val));
    }
}

// Async global->LDS stage of 1KB per wave-instruction: lane l moves 16B from
// g + l*16 to ldsbase + l*16. No result VGPRs -> staging depth is not limited
// by the register allocator; vmcnt counting controls the pipeline.
__device__ __forceinline__ void stage1k(const float* __restrict__ g, float* l) {
    const int lane = threadIdx.x & 63;
    __builtin_amdgcn_global_load_lds(
        (const __attribute__((address_space(1))) void*)(g + lane * 4),
        (__attribute__((address_space(3))) void*)l,
        16, 0, 0);
}

// ---------------- Kernel A: per-edge linear + score + seg-max ---------------
// 16 contiguous edges per block, 256 threads. tid = r*8+t; wave wv owns rows
// 8wv..8wv+7. Per edge, wave wv stages its 4x1KB weight chunks into LDS
// (double-buffered). Software pipeline per wave, no barriers:
//   iter k: [reg loads for e] [stage e+1 -> other buf] [s_waitcnt vmcnt(4)]
//           [ds_read buf k&1, FMA, shuffle-reduce, store, atomicMax]
// vmcnt(4) keeps exactly the 4 newest vmem ops (= edge e+1's staging) in
// flight while guaranteeing edge e's staging has landed -> every wave always
// has ~4KB outstanding; no full drain anywhere in the loop (T3/T4).
__global__ __launch_bounds__(256) void edge_kernel(
    const float* __restrict__ in_feat,  // [N,32]
    const float* __restrict__ query,    // [N,32]
    const float* __restrict__ skw, const float* __restrict__ dkw,
    const float* __restrict__ skb, const float* __restrict__ dkb,
    const float* __restrict__ svw, const float* __restrict__ dvw,
    const float* __restrict__ svb, const float* __restrict__ dvb,
    const int* __restrict__ src, const int* __restrict__ dst,
    float* __restrict__ Kout,   // [E,32] (d_out chunk 1)
    float* __restrict__ Vout,   // [E,32] (d_out chunk 2)
    float* __restrict__ score,  // [E,4]  (workspace)
    float* __restrict__ smax,   // [N,4]  (workspace, pre-initialized to -inf)
    int E)
{
    __shared__ float lds[8192];  // 32KB: [wave 4][buf 2][4 arrays][256 floats]

    const int tid  = threadIdx.x;
    const int lane = tid & 63;
    const int wv   = tid >> 6;   // 0..3
    const int r    = tid >> 3;   // 0..31 (wave wv covers 8wv..8wv+7)
    const int t    = tid & 7;    // 0..7

    const int e0 = blockIdx.x * EPB;
    if (e0 >= E) return;
    const int kmax = (E - e0 < EPB) ? (E - e0) : EPB;

    float* ldsw = &lds[wv * 2048];

    // ---- prologue: indices + stage edge e0 into buf 0 ----
    int s = src[e0];
    int d = dst[e0];
    {
        const size_t g0 = (size_t)e0 * 1024 + (size_t)wv * 256;
        stage1k(skw + g0, ldsw + 0);
        stage1k(dkw + g0, ldsw + 256);
        stage1k(svw + g0, ldsw + 512);
        stage1k(dvw + g0, ldsw + 768);
    }

    for (int k = 0; k < kmax; ++k) {
        const int e = e0 + k;
        const int d_cur = d;

        // ---- 1. register loads for current edge (uses s,d from prefetch) ----
        const float4 u4 = *(const float4*)(in_feat + (size_t)s * DD + t * 4);
        const float4 v4 = *(const float4*)(in_feat + (size_t)d * DD + t * 4);
        const size_t bo = (size_t)e * DD + r;
        const float kb = skb[bo] + dkb[bo];
        const float vb = svb[bo] + dvb[bo];
        const float q  = query[(size_t)d * DD + r];

        // ---- 2. prefetch next indices + stage next edge into other buf ----
        if (k + 1 < kmax) {
            const int en = e + 1;
            s = src[en];
            d = dst[en];
            const size_t gn = (size_t)en * 1024 + (size_t)wv * 256;
            float* nb = ldsw + ((k + 1) & 1) * 1024;
            stage1k(skw + gn, nb + 0);
            stage1k(dkw + gn, nb + 256);
            stage1k(svw + gn, nb + 512);
            stage1k(dvw + gn, nb + 768);
        }

        // ---- 3. wait: drain everything except the 4 newest (= next stage) --
        asm volatile("s_waitcnt vmcnt(4)" ::: "memory");

        // ---- 4. consume current buffer ----
        const float* cb = ldsw + (k & 1) * 1024;
        const int li = lane * 4;
        const float4 a = *(const float4*)(cb + 0   + li);
        const float4 b = *(const float4*)(cb + 256 + li);
        const float4 c = *(const float4*)(cb + 512 + li);
        const float4 g = *(const float4*)(cb + 768 + li);

        float pk = a.x * u4.x + a.y * u4.y + a.z * u4.z + a.w * u4.w
                 + b.x * v4.x + b.y * v4.y + b.z * v4.z + b.w * v4.w;
        float pv = c.x * u4.x + c.y * u4.y + c.z * u4.z + c.w * u4.w
                 + g.x * v4.x + g.y * v4.y + g.z * v4.z + g.w * v4.w;

        // reduce over the 8 column-lanes
        #pragma unroll
        for (int m = 1; m <= 4; m <<= 1) {
            pk += __shfl_xor(pk, m);
            pv += __shfl_xor(pv, m);
        }

        const float kval = pk + kb;
        const float vval = pv + vb;
        if (t == 0) {
            Kout[bo] = kval;
            Vout[bo] = vval;
        }

        // head score: combine the 8 r-groups within the wave
        float prod = kval * q;
        #pragma unroll
        for (int m = 8; m <= 32; m <<= 1) prod += __shfl_xor(prod, m);
        if (lane == 0) {
            score[(size_t)e * HH + wv] = prod;
            atomicMaxFloat(&smax[(size_t)d_cur * HH + wv], prod);
        }
    }
}

// ---------------- Kernel B1: init workspace (runs BEFORE edge_kernel) -------
__global__ void init_kernel(float* __restrict__ smax, float* __restrict__ ssum,
                            float* __restrict__ agg, int NH, int ND)
{
    const int i = blockIdx.x * blockDim.x + threadIdx.x;
    if (i < NH) {
        smax[i] = __int_as_float(0xff800000);  // -inf
        ssum[i] = 0.0f;
    }
    if (i < ND) agg[i] = 0.0f;
}

// ---------------- Kernel B3: exp + segment sum ----------------
__global__ void esum_kernel(const float* __restrict__ score,
                            const int* __restrict__ dst,
                            const float* __restrict__ smax,
                            float* __restrict__ ex, float* __restrict__ ssum,
                            int EH)
{
    const int i = blockIdx.x * blockDim.x + threadIdx.x;
    if (i >= EH) return;
    const int e = i >> 2, h = i & 3;
    const int d = dst[e];
    const float x = expf(score[i] - smax[(size_t)d * HH + h]);
    ex[i] = x;
    atomicAdd(&ssum[(size_t)d * HH + h], x);
}

// ---------------- Kernel B4: attn + weighted scatter-sum ----------------
__global__ void attn_agg_kernel(const float* __restrict__ ex,
                                const float* __restrict__ ssum,
                                const int* __restrict__ dst,
                                const float* __restrict__ V,     // [E,32]
                                float* __restrict__ attn_out,    // [E,4]
                                float* __restrict__ agg,         // [N,32]
                                int ED)
{
    const int i = blockIdx.x * blockDim.x + threadIdx.x;
    if (i >= ED) return;
    const int e = i >> 5, c = i & 31, h = c >> 3;
    const int d = dst[e];
    const float a = ex[(size_t)e * HH + h] / ssum[(size_t)d * HH + h];
    if ((c & 7) == 0) attn_out[(size_t)e * HH + h] = a;
    atomicAdd(&agg[(size_t)d * DD + c], V[i] * a);
}

// ---------------- Kernel C: node linear + relu + residual + LN --------------
__global__ __launch_bounds__(256) void node_kernel(
    const float* __restrict__ in_feat,  // [N,32]
    const float* __restrict__ node_w,   // [N,32,32]
    const float* __restrict__ node_b,   // [N,32]
    const float* __restrict__ agg,      // [N,32]
    const float* __restrict__ ln_g, const float* __restrict__ ln_b,
    float* __restrict__ out, int N)
{
    __shared__ float ys[DD];
    const int n = blockIdx.x;
    if (n >= N) return;
    const int tid = threadIdx.x;
    const int r = tid >> 3, t = tid & 7;

    const float4 a4 = *(const float4*)(agg + (size_t)n * DD + t * 4);
    const float4 w4 = *(const float4*)(node_w + (size_t)n * 1024 + (size_t)r * 32 + t * 4);
    float p = w4.x * a4.x + w4.y * a4.y + w4.z * a4.z + w4.w * a4.w;
    #pragma unroll
    for (int m = 1; m <= 4; m <<= 1) p += __shfl_xor(p, m);
    if (t == 0) {
        float y = p + node_b[(size_t)n * DD + r];
        y = fmaxf(y, 0.0f) + in_feat[(size_t)n * DD + r];
        ys[r] = y;
    }
    __syncthreads();
    if (tid < 64) {
        const float y = (tid < DD) ? ys[tid] : 0.0f;
        float sum = y;
        #pragma unroll
        for (int m = 1; m <= 32; m <<= 1) sum += __shfl_xor(sum, m);
        const float mu = sum * (1.0f / DD);
        const float dy = (tid < DD) ? (y - mu) : 0.0f;
        float s2 = dy * dy;
        #pragma unroll
        for (int m = 1; m <= 32; m <<= 1) s2 += __shfl_xor(s2, m);
        const float var = s2 * (1.0f / DD);
        if (tid < DD) {
            out[(size_t)n * DD + tid] =
                dy * rsqrtf(var + 1e-5f) * ln_g[tid] + ln_b[tid];
        }
    }
}

extern "C" void kernel_launch(void* const* d_in, const int* in_sizes, int n_in,
                              void* d_out, int out_size, void* d_ws, size_t ws_size,
                              hipStream_t stream) {
    const float* in_feat = (const float*)d_in[0];
    const float* query   = (const float*)d_in[1];
    const float* skw     = (const float*)d_in[2];
    const float* dkw     = (const float*)d_in[3];
    const float* skb     = (const float*)d_in[4];
    const float* dkb     = (const float*)d_in[5];
    const float* svw     = (const float*)d_in[6];
    const float* dvw     = (const float*)d_in[7];
    const float* svb     = (const float*)d_in[8];
    const float* dvb     = (const float*)d_in[9];
    const float* node_w  = (const float*)d_in[10];
    const float* node_b  = (const float*)d_in[11];
    const float* ln_g    = (const float*)d_in[12];
    const float* ln_b    = (const float*)d_in[13];
    const int*   src     = (const int*)d_in[14];
    const int*   dst     = (const int*)d_in[15];

    const int N = in_sizes[0] / DD;     // 10000
    const int E = in_sizes[14];         // 50000
    const int NH = N * HH, ND = N * DD;
    const int EH = E * HH, ED = E * DD;

    // d_out layout (return order): out[N,32], K[E,32], V[E,32], attn[E,4]
    float* out_node = (float*)d_out;
    float* Kout     = out_node + (size_t)N * DD;
    float* Vout     = Kout + (size_t)E * DD;
    float* attn_out = Vout + (size_t)E * DD;

    // workspace: score[E*4] | ex[E*4] | smax[N*4] | ssum[N*4] | agg[N*32]
    float* ws    = (float*)d_ws;
    float* score = ws;
    float* ex    = score + EH;
    float* smax  = ex + EH;
    float* ssum  = smax + NH;
    float* agg   = ssum + NH;

    // B1 first: smax must be -inf before edge_kernel's fused atomicMax.
    init_kernel<<<(ND + 255) / 256, 256, 0, stream>>>(smax, ssum, agg, NH, ND);
    // A: per-edge linears + scores + fused segment-max (dominant HBM stream)
    edge_kernel<<<(E + EPB - 1) / EPB, 256, 0, stream>>>(
        in_feat, query, skw, dkw, skb, dkb, svw, dvw, svb, dvb, src, dst,
        Kout, Vout, score, smax, E);
    // B3: exp + segment sum
    esum_kernel<<<(EH + 255) / 256, 256, 0, stream>>>(score, dst, smax, ex, ssum, EH);
    // B4: attn + scatter-sum into agg
    attn_agg_kernel<<<(ED + 255) / 256, 256, 0, stream>>>(ex, ssum, dst, Vout,
                                                          attn_out, agg, ED);
    // C: per-node linear + relu + residual + LayerNorm
    node_kernel<<<N, 256, 0, stream>>>(in_feat, node_w, node_b, agg,
                                       ln_g, ln_b, out_node, N);
}

// Round 6
// 190.843 us; speedup vs baseline: 1.0881x; 1.0881x over previous
//
#include <hip/hip_runtime.h>
#include <hip/hip_bf16.h>
#include <math.h>

// Problem constants (from reference): N=10000, E=50000, D=32, H=4, DH=8
#define DD 32
#define HH 4
#define S_EDGES 32   // edges per block (contiguous span; 128KB per array-pass)

__device__ __forceinline__ void atomicMaxFloat(float* addr, float val) {
    // sign-split trick; addr must be initialized to -inf
    if (val >= 0.0f) {
        atomicMax((int*)addr, __float_as_int(val));
    } else {
        atomicMin((unsigned int*)addr, __float_as_uint(val));
    }
}

__device__ __forceinline__ float dot4(float4 a, float4 b) {
    return a.x * b.x + a.y * b.y + a.z * b.z + a.w * b.w;
}

// One weight-array pass: the block streams W[e0*1KB .. (e0+nE)*1KB) fully
// contiguously (tid*16B within each edge's 4KB page, depth-2 register
// prefetch), dotting rows against LDS-preloaded features and accumulating
// partial row-sums into acc[j][r]. Exactly ONE sequential global stream per
// block in steady state -> maximal DRAM/row locality per CU.
template<bool FIRST>
__device__ __forceinline__ void weight_pass(
    const float* __restrict__ W, size_t e0, int nE,
    const float* __restrict__ featLds,   // [32][32] LDS
    float* __restrict__ acc,             // [32][32] LDS
    int tid)
{
    const int r = tid >> 3, t = tid & 7;
    const float* gbase = W + e0 * 1024 + tid * 4;  // tid*4 == r*32 + t*4
    float4 w0 = *(const float4*)(gbase);
    float4 w1 = (nE > 1) ? *(const float4*)(gbase + 1024) : w0;
    for (int j = 0; j < nE; ++j) {
        const int jp = (j + 2 < nE) ? (j + 2) : (nE - 1);  // clamped prefetch
        const float4 w2 = *(const float4*)(gbase + (size_t)jp * 1024);
        const float4 f = *(const float4*)(featLds + j * 32 + t * 4);
        float p = dot4(w0, f);
        p += __shfl_xor(p, 1);
        p += __shfl_xor(p, 2);
        p += __shfl_xor(p, 4);
        if (t == 0) {
            if (FIRST) acc[j * 32 + r] = p;
            else       acc[j * 32 + r] += p;
        }
        w0 = w1; w1 = w2;
    }
}

// ---------------- Kernel A: per-edge linear + score + seg-max ---------------
// 32 contiguous edges per block, 256 threads, 4 array-major passes:
//   p1: acc  = skw@u   p2: acc += dkw@v   -> epilogue K + score + atomicMax
//   p3: acc  = svw@u   p4: acc += dvw@v   -> epilogue V
// Gathered features (u,v) preloaded once into LDS; biases added in epilogues.
__global__ __launch_bounds__(256) void edge_kernel(
    const float* __restrict__ in_feat,  // [N,32]
    const float* __restrict__ query,    // [N,32]
    const float* __restrict__ skw, const float* __restrict__ dkw,
    const float* __restrict__ skb, const float* __restrict__ dkb,
    const float* __restrict__ svw, const float* __restrict__ dvw,
    const float* __restrict__ svb, const float* __restrict__ dvb,
    const int* __restrict__ src, const int* __restrict__ dst,
    float* __restrict__ Kout,   // [E,32] (d_out chunk 1)
    float* __restrict__ Vout,   // [E,32] (d_out chunk 2)
    float* __restrict__ score,  // [E,4]  (workspace)
    float* __restrict__ smax,   // [N,4]  (workspace, pre-init to -inf)
    int E)
{
    __shared__ int   idx_s[S_EDGES], idx_d[S_EDGES];
    __shared__ float uf[S_EDGES * DD];   // src features
    __shared__ float vf[S_EDGES * DD];   // dst features
    __shared__ float acc[S_EDGES * DD];  // K then V partials

    const int tid = threadIdx.x;
    const int e0i = blockIdx.x * S_EDGES;
    if (e0i >= E) return;
    const size_t e0 = (size_t)e0i;
    const int nE = (E - e0i < S_EDGES) ? (E - e0i) : S_EDGES;

    // ---- indices ----
    if (tid < S_EDGES) {
        int ee = e0i + tid; if (ee >= E) ee = E - 1;
        idx_s[tid] = src[ee];
    } else if (tid < 2 * S_EDGES) {
        int ee = e0i + tid - S_EDGES; if (ee >= E) ee = E - 1;
        idx_d[tid - S_EDGES] = dst[ee];
    }
    __syncthreads();

    // ---- preload gathered features (L2-resident, one-time) ----
    {
        const int j = tid >> 3, t = tid & 7;
        *(float4*)(uf + j * 32 + t * 4) =
            *(const float4*)(in_feat + (size_t)idx_s[j] * DD + t * 4);
        *(float4*)(vf + j * 32 + t * 4) =
            *(const float4*)(in_feat + (size_t)idx_d[j] * DD + t * 4);
    }
    __syncthreads();

    // ---- K passes ----
    weight_pass<true >(skw, e0, nE, uf, acc, tid);
    weight_pass<false>(dkw, e0, nE, vf, acc, tid);
    __syncthreads();

    // ---- epilogue K: bias, store, score, fused segment-max ----
    #pragma unroll
    for (int i = 0; i < S_EDGES / 8; ++i) {
        const int j = i * 8 + (tid >> 5);
        const int r = tid & 31;
        if (j < nE) {
            const size_t e = e0 + j;
            const float kv = acc[j * 32 + r] + skb[e * DD + r] + dkb[e * DD + r];
            Kout[e * DD + r] = kv;
            float p = kv * query[(size_t)idx_d[j] * DD + r];
            p += __shfl_xor(p, 1);
            p += __shfl_xor(p, 2);
            p += __shfl_xor(p, 4);
            if ((r & 7) == 0) {
                const int h = r >> 3;
                score[e * HH + h] = p;
                atomicMaxFloat(&smax[(size_t)idx_d[j] * HH + h], p);
            }
        }
    }
    __syncthreads();  // acc reused below

    // ---- V passes ----
    weight_pass<true >(svw, e0, nE, uf, acc, tid);
    weight_pass<false>(dvw, e0, nE, vf, acc, tid);
    __syncthreads();

    // ---- epilogue V ----
    #pragma unroll
    for (int i = 0; i < S_EDGES / 8; ++i) {
        const int j = i * 8 + (tid >> 5);
        const int r = tid & 31;
        if (j < nE) {
            const size_t e = e0 + j;
            Vout[e * DD + r] = acc[j * 32 + r] + svb[e * DD + r] + dvb[e * DD + r];
        }
    }
}

// ---------------- Kernel B1: init workspace (runs BEFORE edge_kernel) -------
__global__ void init_kernel(float* __restrict__ smax, float* __restrict__ ssum,
                            float* __restrict__ agg, int NH, int ND)
{
    const int i = blockIdx.x * blockDim.x + threadIdx.x;
    if (i < NH) {
        smax[i] = __int_as_float(0xff800000);  // -inf
        ssum[i] = 0.0f;
    }
    if (i < ND) agg[i] = 0.0f;
}

// ---------------- Kernel B3: exp + segment sum ----------------
__global__ void esum_kernel(const float* __restrict__ score,
                            const int* __restrict__ dst,
                            const float* __restrict__ smax,
                            float* __restrict__ ex, float* __restrict__ ssum,
                            int EH)
{
    const int i = blockIdx.x * blockDim.x + threadIdx.x;
    if (i >= EH) return;
    const int e = i >> 2, h = i & 3;
    const int d = dst[e];
    const float x = expf(score[i] - smax[(size_t)d * HH + h]);
    ex[i] = x;
    atomicAdd(&ssum[(size_t)d * HH + h], x);
}

// ---------------- Kernel B4: attn + weighted scatter-sum ----------------
__global__ void attn_agg_kernel(const float* __restrict__ ex,
                                const float* __restrict__ ssum,
                                const int* __restrict__ dst,
                                const float* __restrict__ V,     // [E,32]
                                float* __restrict__ attn_out,    // [E,4]
                                float* __restrict__ agg,         // [N,32]
                                int ED)
{
    const int i = blockIdx.x * blockDim.x + threadIdx.x;
    if (i >= ED) return;
    const int e = i >> 5, c = i & 31, h = c >> 3;
    const int d = dst[e];
    const float a = ex[(size_t)e * HH + h] / ssum[(size_t)d * HH + h];
    if ((c & 7) == 0) attn_out[(size_t)e * HH + h] = a;
    atomicAdd(&agg[(size_t)d * DD + c], V[i] * a);
}

// ---------------- Kernel C: node linear + relu + residual + LN --------------
__global__ __launch_bounds__(256) void node_kernel(
    const float* __restrict__ in_feat,  // [N,32]
    const float* __restrict__ node_w,   // [N,32,32]
    const float* __restrict__ node_b,   // [N,32]
    const float* __restrict__ agg,      // [N,32]
    const float* __restrict__ ln_g, const float* __restrict__ ln_b,
    float* __restrict__ out, int N)
{
    __shared__ float ys[DD];
    const int n = blockIdx.x;
    if (n >= N) return;
    const int tid = threadIdx.x;
    const int r = tid >> 3, t = tid & 7;

    const float4 a4 = *(const float4*)(agg + (size_t)n * DD + t * 4);
    const float4 w4 = *(const float4*)(node_w + (size_t)n * 1024 + (size_t)r * 32 + t * 4);
    float p = w4.x * a4.x + w4.y * a4.y + w4.z * a4.z + w4.w * a4.w;
    #pragma unroll
    for (int m = 1; m <= 4; m <<= 1) p += __shfl_xor(p, m);
    if (t == 0) {
        float y = p + node_b[(size_t)n * DD + r];
        y = fmaxf(y, 0.0f) + in_feat[(size_t)n * DD + r];
        ys[r] = y;
    }
    __syncthreads();
    if (tid < 64) {
        const float y = (tid < DD) ? ys[tid] : 0.0f;
        float sum = y;
        #pragma unroll
        for (int m = 1; m <= 32; m <<= 1) sum += __shfl_xor(sum, m);
        const float mu = sum * (1.0f / DD);
        const float dy = (tid < DD) ? (y - mu) : 0.0f;
        float s2 = dy * dy;
        #pragma unroll
        for (int m = 1; m <= 32; m <<= 1) s2 += __shfl_xor(s2, m);
        const float var = s2 * (1.0f / DD);
        if (tid < DD) {
            out[(size_t)n * DD + tid] =
                dy * rsqrtf(var + 1e-5f) * ln_g[tid] + ln_b[tid];
        }
    }
}

extern "C" void kernel_launch(void* const* d_in, const int* in_sizes, int n_in,
                              void* d_out, int out_size, void* d_ws, size_t ws_size,
                              hipStream_t stream) {
    const float* in_feat = (const float*)d_in[0];
    const float* query   = (const float*)d_in[1];
    const float* skw     = (const float*)d_in[2];
    const float* dkw     = (const float*)d_in[3];
    const float* skb     = (const float*)d_in[4];
    const float* dkb     = (const float*)d_in[5];
    const float* svw     = (const float*)d_in[6];
    const float* dvw     = (const float*)d_in[7];
    const float* svb     = (const float*)d_in[8];
    const float* dvb     = (const float*)d_in[9];
    const float* node_w  = (const float*)d_in[10];
    const float* node_b  = (const float*)d_in[11];
    const float* ln_g    = (const float*)d_in[12];
    const float* ln_b    = (const float*)d_in[13];
    const int*   src     = (const int*)d_in[14];
    const int*   dst     = (const int*)d_in[15];

    const int N = in_sizes[0] / DD;     // 10000
    const int E = in_sizes[14];         // 50000
    const int NH = N * HH, ND = N * DD;
    const int EH = E * HH, ED = E * DD;

    // d_out layout (return order): out[N,32], K[E,32], V[E,32], attn[E,4]
    float* out_node = (float*)d_out;
    float* Kout     = out_node + (size_t)N * DD;
    float* Vout     = Kout + (size_t)E * DD;
    float* attn_out = Vout + (size_t)E * DD;

    // workspace: score[E*4] | ex[E*4] | smax[N*4] | ssum[N*4] | agg[N*32]
    float* ws    = (float*)d_ws;
    float* score = ws;
    float* ex    = score + EH;
    float* smax  = ex + EH;
    float* ssum  = smax + NH;
    float* agg   = ssum + NH;

    // B1 first: smax must be -inf before edge_kernel's fused atomicMax.
    init_kernel<<<(ND + 255) / 256, 256, 0, stream>>>(smax, ssum, agg, NH, ND);
    // A: per-edge linears + scores + fused segment-max (dominant HBM stream)
    edge_kernel<<<(E + S_EDGES - 1) / S_EDGES, 256, 0, stream>>>(
        in_feat, query, skw, dkw, skb, dkb, svw, dvw, svb, dvb, src, dst,
        Kout, Vout, score, smax, E);
    // B3: exp + segment sum
    esum_kernel<<<(EH + 255) / 256, 256, 0, stream>>>(score, dst, smax, ex, ssum, EH);
    // B4: attn + scatter-sum into agg
    attn_agg_kernel<<<(ED + 255) / 256, 256, 0, stream>>>(ex, ssum, dst, Vout,
                                                          attn_out, agg, ED);
    // C: per-node linear + relu + residual + LayerNorm
    node_kernel<<<N, 256, 0, stream>>>(in_feat, node_w, node_b, agg,
                                       ln_g, ln_b, out_node, N);
}

// Round 7
// 186.043 us; speedup vs baseline: 1.1162x; 1.0258x over previous
//
#include <hip/hip_runtime.h>
#include <hip/hip_bf16.h>
#include <math.h>

// Problem constants (from reference): N=10000, E=50000, D=32, H=4, DH=8
#define DD 32
#define HH 4

__device__ __forceinline__ void atomicMaxFloat(float* addr, float val) {
    // sign-split trick; addr must be initialized to -inf
    if (val >= 0.0f) {
        atomicMax((int*)addr, __float_as_int(val));
    } else {
        atomicMin((unsigned int*)addr, __float_as_uint(val));
    }
}

// ---------------- Kernel A: per-edge linear + score + seg-max ---------------
// One block (256 threads) per edge — the best-measured structure (R1: 181us
// total; persistent/ILP/async-LDS/stream-major variants all benchmarked
// equal-or-worse; delivery is pinned at ~5.3 TB/s mixed L3+HBM regardless of
// schedule). tid = r*8 + t, r in [0,32): output row (h*8+dh), t in [0,8):
// column quarter; each thread loads a float4 of each weight row (coalesced
// 16KB/block stream), 8-lane shuffle-reduce per row -> K,V rows; per-wave
// (= per-head) shuffle-reduce of K.query[dst] -> score; lane0 fuses the
// segment-max atomic (saves the separate smax pass over score+dst).
__global__ __launch_bounds__(256) void edge_kernel(
    const float* __restrict__ in_feat,  // [N,32]
    const float* __restrict__ query,    // [N,32]
    const float* __restrict__ skw, const float* __restrict__ dkw,
    const float* __restrict__ skb, const float* __restrict__ dkb,
    const float* __restrict__ svw, const float* __restrict__ dvw,
    const float* __restrict__ svb, const float* __restrict__ dvb,
    const int* __restrict__ src, const int* __restrict__ dst,
    float* __restrict__ Kout,   // [E,32] (d_out chunk 1)
    float* __restrict__ Vout,   // [E,32] (d_out chunk 2)
    float* __restrict__ score,  // [E,4]  (workspace)
    float* __restrict__ smax,   // [N,4]  (workspace, pre-init to -inf)
    int E)
{
    const int e = blockIdx.x;
    if (e >= E) return;
    const int tid = threadIdx.x;
    const int r = tid >> 3;   // 0..31
    const int t = tid & 7;    // 0..7

    const int s = src[e];
    const int d = dst[e];

    const float4 u4 = *(const float4*)(in_feat + (size_t)s * DD + t * 4);
    const float4 v4 = *(const float4*)(in_feat + (size_t)d * DD + t * 4);

    const size_t woff = (size_t)e * 1024 + (size_t)r * 32 + (size_t)t * 4;

    float4 a = *(const float4*)(skw + woff);
    float4 b = *(const float4*)(dkw + woff);
    float pk = a.x * u4.x + a.y * u4.y + a.z * u4.z + a.w * u4.w
             + b.x * v4.x + b.y * v4.y + b.z * v4.z + b.w * v4.w;

    float4 c = *(const float4*)(svw + woff);
    float4 g = *(const float4*)(dvw + woff);
    float pv = c.x * u4.x + c.y * u4.y + c.z * u4.z + c.w * u4.w
             + g.x * v4.x + g.y * v4.y + g.z * v4.z + g.w * v4.w;

    // reduce over the 8 column-lanes (contiguous lanes within groups of 8)
    #pragma unroll
    for (int m = 1; m <= 4; m <<= 1) {
        pk += __shfl_xor(pk, m);
        pv += __shfl_xor(pv, m);
    }

    float kval = 0.0f, q = 0.0f;
    if (t == 0) {
        const size_t bo = (size_t)e * DD + r;
        kval = pk + skb[bo] + dkb[bo];
        float vval = pv + svb[bo] + dvb[bo];
        Kout[bo] = kval;
        Vout[bo] = vval;
        q = query[(size_t)d * DD + r];
    }
    // score_h = sum_dh K[h,dh]*q[h,dh]; wave w holds rows 8w..8w+7 (head w)
    float prod = kval * q;   // zero on t!=0 lanes
    #pragma unroll
    for (int m = 8; m <= 32; m <<= 1) prod += __shfl_xor(prod, m);
    if ((tid & 63) == 0) {
        const int h = tid >> 6;   // wave id == head id
        score[(size_t)e * HH + h] = prod;
        atomicMaxFloat(&smax[(size_t)d * HH + h], prod);  // fused segment-max
    }
}

// ---------------- Kernel B1: init workspace (runs BEFORE edge_kernel) ------
__global__ void init_kernel(float* __restrict__ smax, float* __restrict__ ssum,
                            float* __restrict__ agg, int NH, int ND)
{
    const int i = blockIdx.x * blockDim.x + threadIdx.x;
    if (i < NH) {
        smax[i] = __int_as_float(0xff800000);  // -inf
        ssum[i] = 0.0f;
    }
    if (i < ND) agg[i] = 0.0f;
}

// ---------------- Kernel B3: exp + segment sum ----------------
__global__ void esum_kernel(const float* __restrict__ score,
                            const int* __restrict__ dst,
                            const float* __restrict__ smax,
                            float* __restrict__ ex, float* __restrict__ ssum,
                            int EH)
{
    const int i = blockIdx.x * blockDim.x + threadIdx.x;
    if (i >= EH) return;
    const int e = i >> 2, h = i & 3;
    const int d = dst[e];
    const float x = expf(score[i] - smax[(size_t)d * HH + h]);
    ex[i] = x;
    atomicAdd(&ssum[(size_t)d * HH + h], x);
}

// ---------------- Kernel B4: attn + weighted scatter-sum ----------------
__global__ void attn_agg_kernel(const float* __restrict__ ex,
                                const float* __restrict__ ssum,
                                const int* __restrict__ dst,
                                const float* __restrict__ V,     // [E,32]
                                float* __restrict__ attn_out,    // [E,4]
                                float* __restrict__ agg,         // [N,32]
                                int ED)
{
    const int i = blockIdx.x * blockDim.x + threadIdx.x;
    if (i >= ED) return;
    const int e = i >> 5, c = i & 31, h = c >> 3;
    const int d = dst[e];
    const float a = ex[(size_t)e * HH + h] / ssum[(size_t)d * HH + h];
    if ((c & 7) == 0) attn_out[(size_t)e * HH + h] = a;
    atomicAdd(&agg[(size_t)d * DD + c], V[i] * a);
}

// ---------------- Kernel C: node linear + relu + residual + LN --------------
__global__ __launch_bounds__(256) void node_kernel(
    const float* __restrict__ in_feat,  // [N,32]
    const float* __restrict__ node_w,   // [N,32,32]
    const float* __restrict__ node_b,   // [N,32]
    const float* __restrict__ agg,      // [N,32]
    const float* __restrict__ ln_g, const float* __restrict__ ln_b,
    float* __restrict__ out, int N)
{
    __shared__ float ys[DD];
    const int n = blockIdx.x;
    if (n >= N) return;
    const int tid = threadIdx.x;
    const int r = tid >> 3, t = tid & 7;

    const float4 a4 = *(const float4*)(agg + (size_t)n * DD + t * 4);
    const float4 w4 = *(const float4*)(node_w + (size_t)n * 1024 + (size_t)r * 32 + t * 4);
    float p = w4.x * a4.x + w4.y * a4.y + w4.z * a4.z + w4.w * a4.w;
    #pragma unroll
    for (int m = 1; m <= 4; m <<= 1) p += __shfl_xor(p, m);
    if (t == 0) {
        float y = p + node_b[(size_t)n * DD + r];
        y = fmaxf(y, 0.0f) + in_feat[(size_t)n * DD + r];
        ys[r] = y;
    }
    __syncthreads();
    if (tid < 64) {
        const float y = (tid < DD) ? ys[tid] : 0.0f;
        float sum = y;
        #pragma unroll
        for (int m = 1; m <= 32; m <<= 1) sum += __shfl_xor(sum, m);
        const float mu = sum * (1.0f / DD);
        const float dy = (tid < DD) ? (y - mu) : 0.0f;
        float s2 = dy * dy;
        #pragma unroll
        for (int m = 1; m <= 32; m <<= 1) s2 += __shfl_xor(s2, m);
        const float var = s2 * (1.0f / DD);
        if (tid < DD) {
            out[(size_t)n * DD + tid] =
                dy * rsqrtf(var + 1e-5f) * ln_g[tid] + ln_b[tid];
        }
    }
}

extern "C" void kernel_launch(void* const* d_in, const int* in_sizes, int n_in,
                              void* d_out, int out_size, void* d_ws, size_t ws_size,
                              hipStream_t stream) {
    const float* in_feat = (const float*)d_in[0];
    const float* query   = (const float*)d_in[1];
    const float* skw     = (const float*)d_in[2];
    const float* dkw     = (const float*)d_in[3];
    const float* skb     = (const float*)d_in[4];
    const float* dkb     = (const float*)d_in[5];
    const float* svw     = (const float*)d_in[6];
    const float* dvw     = (const float*)d_in[7];
    const float* svb     = (const float*)d_in[8];
    const float* dvb     = (const float*)d_in[9];
    const float* node_w  = (const float*)d_in[10];
    const float* node_b  = (const float*)d_in[11];
    const float* ln_g    = (const float*)d_in[12];
    const float* ln_b    = (const float*)d_in[13];
    const int*   src     = (const int*)d_in[14];
    const int*   dst     = (const int*)d_in[15];

    const int N = in_sizes[0] / DD;     // 10000
    const int E = in_sizes[14];         // 50000
    const int NH = N * HH, ND = N * DD;
    const int EH = E * HH, ED = E * DD;

    // d_out layout (return order): out[N,32], K[E,32], V[E,32], attn[E,4]
    float* out_node = (float*)d_out;
    float* Kout     = out_node + (size_t)N * DD;
    float* Vout     = Kout + (size_t)E * DD;
    float* attn_out = Vout + (size_t)E * DD;

    // workspace: score[E*4] | ex[E*4] | smax[N*4] | ssum[N*4] | agg[N*32]
    float* ws    = (float*)d_ws;
    float* score = ws;
    float* ex    = score + EH;
    float* smax  = ex + EH;
    float* ssum  = smax + NH;
    float* agg   = ssum + NH;

    // B1 first: smax must be -inf before edge_kernel's fused atomicMax.
    init_kernel<<<(ND + 255) / 256, 256, 0, stream>>>(smax, ssum, agg, NH, ND);
    // A: per-edge linears + scores + fused segment-max (dominant HBM stream)
    edge_kernel<<<E, 256, 0, stream>>>(in_feat, query, skw, dkw, skb, dkb,
                                       svw, dvw, svb, dvb, src, dst,
                                       Kout, Vout, score, smax, E);
    // B3: exp + segment sum
    esum_kernel<<<(EH + 255) / 256, 256, 0, stream>>>(score, dst, smax, ex, ssum, EH);
    // B4: attn + scatter-sum into agg
    attn_agg_kernel<<<(ED + 255) / 256, 256, 0, stream>>>(ex, ssum, dst, Vout,
                                                          attn_out, agg, ED);
    // C: per-node linear + relu + residual + LayerNorm
    node_kernel<<<N, 256, 0, stream>>>(in_feat, node_w, node_b, agg,
                                       ln_g, ln_b, out_node, N);
}